// Round 17
// baseline (200.074 us; speedup 1.0000x reference)
//
#include <hip/hip_runtime.h>
#include <math.h>

#define SQRT3F 1.7320508075688772f
#define INV_SQRT3F 0.57735026918962576f
typedef unsigned long long u64;
typedef unsigned int u32;

// bin packing: [x:19][y:19][z:19][count:7], per-addend scale 1024, bias 2048
#define PK_SCALE 1024.0f
#define PK_MASK  0x7FFFFull

// main path: 2048-node ranges, 4B topology records, block counting-sort
#define NPR2   2048
#define NRG2   49                       // 49*2048 = 100352 >= N
#define REP2   ((size_t)NRG2 * NPR2)    // u64 per replica
#define EPB    4096                     // edges per scatter block (8/thread @512)
#define NWAVE  8                        // waves per 512-thread scatter block

// fallback (round-6 kernel)
#define NPR    4096
#define NRANGE 25

__device__ __forceinline__ float gelu_exact(float x) {
    return 0.5f * x * (1.0f + erff(x * 0.70710678118654752f));
}

// fp32 sh components -> packed bin addend (scale 1024, bias 2048 per addend)
__device__ __forceinline__ u64 sh_to_w(float rx, float ry, float rz) {
    float rr = sqrtf(rx*rx + ry*ry + rz*rz);
    float inv = (SQRT3F * PK_SCALE) / fmaxf(rr, 1e-9f);
    u32 ax = (u32)__float2int_rn(rx * inv) + 2048u;
    u32 ay = (u32)__float2int_rn(ry * inv) + 2048u;
    u32 az = (u32)__float2int_rn(rz * inv) + 2048u;
    return (u64)ax | ((u64)ay << 19) | ((u64)az << 38) | (1ull << 57);
}

// decoded meanSh -> per-node pooled contribution sf[5] (closed-form 3 layers)
__device__ void node_math(const float m[3],
    const float* __restrict__ W0_1, const float* __restrict__ W1_1, const float* __restrict__ b_1,
    const float* __restrict__ Wg1,  const float* __restrict__ bg1,
    const float* __restrict__ W0_2, const float* __restrict__ W1_2, const float* __restrict__ b_2,
    const float* __restrict__ Wg2,  const float* __restrict__ bg2,
    const float* __restrict__ W0_3, const float* __restrict__ b_3,
    const float* __restrict__ Wg3,  const float* __restrict__ bg3,
    float sf[5])
{
    float s1[5], v1[5][3];
    #pragma unroll
    for (int i = 0; i < 5; ++i) {
        s1[i] = W0_1[i] + b_1[i];
        #pragma unroll
        for (int c = 0; c < 3; ++c) v1[i][c] = W1_1[i*3+c] * m[c];
    }
    float g1[10];
    #pragma unroll
    for (int j = 0; j < 10; ++j) {
        float t = bg1[j];
        #pragma unroll
        for (int i = 0; i < 5; ++i) t += Wg1[j*5+i] * s1[i];
        g1[j] = gelu_exact(t);
    }
    #pragma unroll
    for (int i = 0; i < 5; ++i) {
        s1[i] *= g1[i];
        #pragma unroll
        for (int c = 0; c < 3; ++c) v1[i][c] *= g1[5+i];
    }
    float dot1[5];
    #pragma unroll
    for (int i = 0; i < 5; ++i)
        dot1[i] = (v1[i][0]*m[0] + v1[i][1]*m[1] + v1[i][2]*m[2]) * INV_SQRT3F;
    float s2[5];
    #pragma unroll
    for (int o = 0; o < 5; ++o) {
        float t = b_2[o];
        #pragma unroll
        for (int i = 0; i < 5; ++i) t += W0_2[o*10+i] * s1[i];
        #pragma unroll
        for (int i = 0; i < 5; ++i) t += W0_2[o*10+5+i] * dot1[i];
        s2[o] = t;
    }
    float v2[5][3];
    #pragma unroll
    for (int o = 0; o < 5; ++o) {
        #pragma unroll
        for (int c = 0; c < 3; ++c) {
            float t = 0.f;
            #pragma unroll
            for (int i = 0; i < 5; ++i) {
                t += W1_2[(o*10+i)*3+c]   * (s1[i] * m[c]);
                t += W1_2[(o*10+5+i)*3+c] * v1[i][c];
            }
            v2[o][c] = t;
        }
    }
    float g2[10];
    #pragma unroll
    for (int j = 0; j < 10; ++j) {
        float t = bg2[j];
        #pragma unroll
        for (int i = 0; i < 5; ++i) t += Wg2[j*5+i] * s2[i];
        g2[j] = gelu_exact(t);
    }
    #pragma unroll
    for (int i = 0; i < 5; ++i) {
        s2[i] *= g2[i];
        #pragma unroll
        for (int c = 0; c < 3; ++c) v2[i][c] *= g2[5+i];
    }
    float dot2[5];
    #pragma unroll
    for (int i = 0; i < 5; ++i)
        dot2[i] = (v2[i][0]*m[0] + v2[i][1]*m[1] + v2[i][2]*m[2]) * INV_SQRT3F;
    float s3[5];
    #pragma unroll
    for (int o = 0; o < 5; ++o) {
        float t = b_3[o];
        #pragma unroll
        for (int i = 0; i < 5; ++i) t += W0_3[o*10+i] * s2[i];
        #pragma unroll
        for (int i = 0; i < 5; ++i) t += W0_3[o*10+5+i] * dot2[i];
        s3[o] = t;
    }
    #pragma unroll
    for (int i = 0; i < 5; ++i) {
        float t = bg3[i];
        #pragma unroll
        for (int j = 0; j < 5; ++j) t += Wg3[i*5+j] * s3[j];
        sf[i] += gelu_exact(t) * s3[i];
    }
}

// ---- Phase 1 (fused): blocks [0,P) counting-sort 4096 edges @512thr;
// blocks [P,..) pack pos->float4 and zero tickets.
__global__ __launch_bounds__(512) void scatter_pack_kernel(
    const float* __restrict__ pos, float4* __restrict__ pos4,
    const int* __restrict__ src, const int* __restrict__ dst,
    u32* __restrict__ gbuf, u32* __restrict__ cnts,
    u32* __restrict__ done, u32* __restrict__ rtick,
    int E, int N, int P)
{
    const int p = blockIdx.x;
    if (p >= P) {                        // ---- pack duty ----
        int i = (p - P) * 512 + (int)threadIdx.x;
        if (i < N) pos4[i] = make_float4(pos[3*i], pos[3*i+1], pos[3*i+2], 0.f);
        if (p == P && threadIdx.x < 64) {
            if (threadIdx.x == 0) *done = 0;
            if (threadIdx.x < NRG2) rtick[threadIdx.x] = 0;
        }
        return;
    }

    __shared__ u32 whist[NWAVE][NRG2];   // per-wave histograms -> abs bases
    __shared__ u32 base[NRG2];
    __shared__ u32 hist[NRG2];
    __shared__ alignas(16) u32 recbuf[EPB];

    const int wid = threadIdx.x >> 6;
    for (int j = threadIdx.x; j < NWAVE * NRG2; j += 512)
        (&whist[0][0])[j] = 0;
    __syncthreads();

    const int start = p * EPB;
    int end = start + EPB;
    if (end > E) end = E;

    int nk = 0;
    int r[8];
    u32 rec[8], rank[8];
    {
        int d[8], s[8];
        int i0 = start + (int)threadIdx.x * 8;
        if (i0 + 8 <= end) {
            int4 da = *reinterpret_cast<const int4*>(dst + i0);
            int4 db = *reinterpret_cast<const int4*>(dst + i0 + 4);
            int4 sa = *reinterpret_cast<const int4*>(src + i0);
            int4 sb = *reinterpret_cast<const int4*>(src + i0 + 4);
            d[0]=da.x; d[1]=da.y; d[2]=da.z; d[3]=da.w;
            d[4]=db.x; d[5]=db.y; d[6]=db.z; d[7]=db.w;
            s[0]=sa.x; s[1]=sa.y; s[2]=sa.z; s[3]=sa.w;
            s[4]=sb.x; s[5]=sb.y; s[6]=sb.z; s[7]=sb.w;
            nk = 8;
        } else if (i0 < end) {
            nk = end - i0;
            for (int k = 0; k < nk; ++k) { d[k] = dst[i0+k]; s[k] = src[i0+k]; }
        }
        for (int k = 0; k < nk; ++k) {
            r[k] = d[k] >> 11;
            rec[k] = ((u32)s[k] << 11) | ((u32)d[k] & 2047u);
        }
    }
    // single atomic pass: return value = rank within (wave, range)
    for (int k = 0; k < nk; ++k) rank[k] = atomicAdd(&whist[wid][r[k]], 1u);
    __syncthreads();

    if (threadIdx.x < NRG2) {            // column prefix over the 8 waves
        const int rr = threadIdx.x;
        u32 acc = 0;
        #pragma unroll
        for (int w = 0; w < NWAVE; ++w) {
            u32 t = whist[w][rr];
            whist[w][rr] = acc;
            acc += t;
        }
        hist[rr] = acc;
    }
    __syncthreads();

    if (threadIdx.x < 64) {              // shfl exclusive scan over 49 totals
        int lane = threadIdx.x;
        u32 h = (lane < NRG2) ? hist[lane] : 0;
        u32 v = h;
        #pragma unroll
        for (int off = 1; off < 64; off <<= 1) {
            u32 t = __shfl_up(v, off);
            if (lane >= off) v += t;
        }
        if (lane < NRG2) base[lane] = v - h;
    }
    __syncthreads();

    for (int k = 0; k < nk; ++k)         // atomic-free placement
        recbuf[base[r[k]] + whist[wid][r[k]] + rank[k]] = rec[k];
    __syncthreads();

    const int total = end - start;
    u32* out = gbuf + (size_t)p * EPB;
    const int total4 = total & ~3;
    uint4* out4 = reinterpret_cast<uint4*>(out);
    const uint4* rb4 = reinterpret_cast<const uint4*>(recbuf);
    for (int j = threadIdx.x; j * 4 < total4; j += 512) out4[j] = rb4[j];
    for (int j = total4 + threadIdx.x; j < total; j += 512) out[j] = recbuf[j];
    if (threadIdx.x < NRG2)
        cnts[p * NRG2 + threadIdx.x] = (base[threadIdx.x] << 16) | hist[threadIdx.x];
}

// ---- Phase 2 (fused): gather + per-range last-block node math + finalize --
__global__ __launch_bounds__(256) void gather_node_kernel(
    const float4* __restrict__ pos4,
    const u32* __restrict__ gbuf, const u32* __restrict__ cnts,
    u64* __restrict__ reps, u32* __restrict__ rtick, u32* __restrict__ done,
    float* __restrict__ partials, int P, int R2, int N,
    const float* __restrict__ W0_1, const float* __restrict__ W1_1, const float* __restrict__ b_1,
    const float* __restrict__ Wg1,  const float* __restrict__ bg1,
    const float* __restrict__ W0_2, const float* __restrict__ W1_2, const float* __restrict__ b_2,
    const float* __restrict__ Wg2,  const float* __restrict__ bg2,
    const float* __restrict__ W0_3, const float* __restrict__ b_3,
    const float* __restrict__ Wg3,  const float* __restrict__ bg3,
    const float* __restrict__ Wout, const float* __restrict__ bout,
    float* __restrict__ out, float invN)
{
    __shared__ u64 bins[NPR2];       // 16 KB
    __shared__ u32 segn[64];
    const int r  = blockIdx.x % NRG2;
    const int c2 = blockIdx.x / NRG2;
    const int base = r * NPR2;
    const float4* posd = pos4 + base;

    for (int j = threadIdx.x; j < NPR2; j += 256) bins[j] = 0;
    const int nseg = (P - c2 + R2 - 1) / R2;
    for (int t = threadIdx.x; t < nseg; t += 256)
        segn[t] = cnts[(c2 + t * R2) * NRG2 + r];
    __syncthreads();

    const int wid = threadIdx.x >> 6, lane = threadIdx.x & 63;
    for (int sgi = wid; sgi < nseg; sgi += 4) {          // wave-per-segment
        const int p = c2 + sgi * R2;
        const u32 bc = segn[sgi];
        const u32 n = bc & 0xFFFFu;
        const u32* seg = gbuf + (size_t)p * EPB + (bc >> 16);
        for (u32 t = lane; t < n; t += 128) {
            u32 rec0 = seg[t];
            bool h1 = (t + 64) < n;
            u32 rec1 = h1 ? seg[t + 64] : 0;
            u32 j0 = rec0 & 2047u, s0 = rec0 >> 11;
            float4 ps0 = pos4[s0];
            float4 pd0 = posd[j0];
            u32 j1 = rec1 & 2047u, s1 = rec1 >> 11;
            float4 ps1, pd1;
            if (h1) { ps1 = pos4[s1]; pd1 = posd[j1]; }
            atomicAdd(&bins[j0], sh_to_w(pd0.x-ps0.x, pd0.y-ps0.y, pd0.z-ps0.z));
            if (h1)
                atomicAdd(&bins[j1], sh_to_w(pd1.x-ps1.x, pd1.y-ps1.y, pd1.z-ps1.z));
        }
    }
    __syncthreads();

    // flush this replica slice, then take the per-range ticket
    u64* outp = reps + (size_t)c2 * REP2 + base;
    for (int j = threadIdx.x; j < NPR2; j += 256) outp[j] = bins[j];

    __shared__ int lastflag;
    if (threadIdx.x == 0) {
        __threadfence();
        lastflag = (atomicAdd(&rtick[r], 1u) == (u32)(R2 - 1));
    }
    __syncthreads();
    if (!lastflag) return;
    __threadfence();

    // ---- last block for range r: sum other replicas into bins ----
    for (int c = 0; c < R2; ++c) {
        if (c == c2) continue;
        const u64* sl = reps + (size_t)c * REP2 + base;
        for (int j = threadIdx.x; j < NPR2; j += 256) bins[j] += sl[j];
    }
    __syncthreads();

    // ---- node math: 8 nodes per thread, accumulate pooled sf ----
    float sf[5] = {0.f, 0.f, 0.f, 0.f, 0.f};
    for (int q = 0; q < NPR2 / 256; ++q) {
        u64 w = bins[q * 256 + threadIdx.x];
        u32 deg = (u32)(w >> 57);
        if (deg > 0) {
            long long bs = (long long)deg << 11;
            float invdS = 1.0f / (PK_SCALE * (float)deg);
            float m[3];
            m[0] = (float)((long long)( w        & PK_MASK) - bs) * invdS;
            m[1] = (float)((long long)((w >> 19) & PK_MASK) - bs) * invdS;
            m[2] = (float)((long long)((w >> 38) & PK_MASK) - bs) * invdS;
            node_math(m, W0_1, W1_1, b_1, Wg1, bg1, W0_2, W1_2, b_2, Wg2, bg2,
                      W0_3, b_3, Wg3, bg3, sf);
        }
    }

    // reduce sf across the block -> partials[r]
    #pragma unroll
    for (int k = 0; k < 5; ++k) {
        float v = sf[k];
        for (int off = 32; off > 0; off >>= 1) v += __shfl_down(v, off);
        sf[k] = v;
    }
    __shared__ float lred[4][5];
    if (lane == 0) {
        #pragma unroll
        for (int k = 0; k < 5; ++k) lred[wid][k] = sf[k];
    }
    __syncthreads();
    if (threadIdx.x == 0) {
        #pragma unroll
        for (int k = 0; k < 5; ++k)
            partials[r * 5 + k] = lred[0][k] + lred[1][k] + lred[2][k] + lred[3][k];
        __threadfence();
        lastflag = (atomicAdd(done, 1u) == NRG2 - 1);
    }
    __syncthreads();
    if (!lastflag) return;
    __threadfence();

    // ---- final: pool 49 ranges -> softmax ----
    if (threadIdx.x == 0) {
        float pooled[5] = {0.f, 0.f, 0.f, 0.f, 0.f};
        for (int rr = 0; rr < NRG2; ++rr) {
            #pragma unroll
            for (int k = 0; k < 5; ++k) pooled[k] += partials[rr * 5 + k];
        }
        #pragma unroll
        for (int k = 0; k < 5; ++k) pooled[k] *= invN;
        float lg[10], mx = -1e30f;
        #pragma unroll
        for (int j = 0; j < 10; ++j) {
            float t = bout[j];
            #pragma unroll
            for (int i = 0; i < 5; ++i) t += Wout[j*5+i] * pooled[i];
            lg[j] = t;
            mx = fmaxf(mx, t);
        }
        float se = 0.f;
        #pragma unroll
        for (int j = 0; j < 10; ++j) { lg[j] = expf(lg[j] - mx); se += lg[j]; }
        float inv = 1.0f / se;
        #pragma unroll
        for (int j = 0; j < 10; ++j) out[j] = lg[j] * inv;
    }
}

// ---- Fallback (round-6): LDS range-bin with wave compaction ---------------
__global__ __launch_bounds__(256, 4) void edge_bin_kernel(
    const float* __restrict__ pos,
    const int* __restrict__ src,
    const int* __restrict__ dst,
    u64* __restrict__ reps, int E, int span)
{
    __shared__ u64 bins[NPR];
    __shared__ u32 q[4][128];
    const int g = blockIdx.x;
    const int xcd = g & 7;
    const int slot = g >> 3;
    const int c = xcd + 8 * (slot / NRANGE);
    const int r = slot % NRANGE;
    const int base = r * NPR;
    const int lane = threadIdx.x & 63;
    const int wid  = threadIdx.x >> 6;
    const u64 ltmask = (1ull << lane) - 1ull;

    for (int j = threadIdx.x; j < NPR; j += 256) bins[j] = 0;
    __syncthreads();

    const int start = c * span;
    int end = start + span;
    if (end > E) end = E;
    const int niter = (end > start) ? ((end - start + 1023) >> 10) : 0;
    int qcount = 0;

    auto process = [&](u32 i2) {
        int s2 = src[i2]; int d2 = dst[i2];
        u32 j = (u32)(d2 - base);
        atomicAdd(&bins[j], sh_to_w(pos[3*d2+0]-pos[3*s2+0],
                                    pos[3*d2+1]-pos[3*s2+1],
                                    pos[3*d2+2]-pos[3*s2+2]));
    };

    for (int t = 0; t < niter; ++t) {
        int i0 = start + ((int)threadIdx.x << 2) + (t << 10);
        int4 d4 = make_int4(-1, -1, -1, -1);
        if (i0 + 4 <= end) d4 = *reinterpret_cast<const int4*>(dst + i0);
        else if (i0 < end) for (int k = 0; i0 + k < end; ++k) (&d4.x)[k] = dst[i0 + k];
        #pragma unroll
        for (int k = 0; k < 4; ++k) {
            int i = i0 + k;
            bool in = (i < end) && ((u32)((&d4.x)[k] - base) < NPR);
            u64 mask = __ballot(in);
            if (in) q[wid][qcount + __popcll(mask & ltmask)] = (u32)i;
            qcount += (int)__popcll(mask);
            if (qcount >= 64) { qcount -= 64; process(q[wid][qcount + lane]); }
        }
    }
    if (lane < qcount) process(q[wid][lane]);
    __syncthreads();

    u64* outp = reps + (size_t)c * ((size_t)NRANGE * NPR) + base;
    for (int j = threadIdx.x; j < NPR; j += 256) outp[j] = bins[j];
}

// ---- fallback node kernel (separate pass) ---------------------------------
__global__ __launch_bounds__(256) void node_kernel(
    const u64* __restrict__ reps, size_t repStride, int R,
    const float* __restrict__ W0_1, const float* __restrict__ W1_1, const float* __restrict__ b_1,
    const float* __restrict__ Wg1,  const float* __restrict__ bg1,
    const float* __restrict__ W0_2, const float* __restrict__ W1_2, const float* __restrict__ b_2,
    const float* __restrict__ Wg2,  const float* __restrict__ bg2,
    const float* __restrict__ W0_3, const float* __restrict__ b_3,
    const float* __restrict__ Wg3,  const float* __restrict__ bg3,
    float* __restrict__ partials, int N)
{
    int d = blockIdx.x * blockDim.x + threadIdx.x;
    float sf[5] = {0.f, 0.f, 0.f, 0.f, 0.f};

    if (d < N) {
        u64 w = 0;
        for (int r = 0; r < R; ++r) w += reps[(size_t)r * repStride + (u32)d];
        u32 deg = (u32)(w >> 57);
        if (deg > 0) {
            long long bs = (long long)deg << 11;
            float invdS = 1.0f / (PK_SCALE * (float)deg);
            float m[3];
            m[0] = (float)((long long)( w        & PK_MASK) - bs) * invdS;
            m[1] = (float)((long long)((w >> 19) & PK_MASK) - bs) * invdS;
            m[2] = (float)((long long)((w >> 38) & PK_MASK) - bs) * invdS;
            node_math(m, W0_1, W1_1, b_1, Wg1, bg1, W0_2, W1_2, b_2, Wg2, bg2,
                      W0_3, b_3, Wg3, bg3, sf);
        }
    }

    #pragma unroll
    for (int k = 0; k < 5; ++k) {
        float v = sf[k];
        for (int off = 32; off > 0; off >>= 1) v += __shfl_down(v, off);
        sf[k] = v;
    }
    __shared__ float lred[4][5];
    int wid = threadIdx.x >> 6, lane = threadIdx.x & 63;
    if (lane == 0) {
        #pragma unroll
        for (int k = 0; k < 5; ++k) lred[wid][k] = sf[k];
    }
    __syncthreads();
    if (threadIdx.x == 0) {
        #pragma unroll
        for (int k = 0; k < 5; ++k)
            partials[blockIdx.x * 5 + k] = lred[0][k] + lred[1][k] + lred[2][k] + lred[3][k];
    }
}

// standalone finalize (fallback path only)
__global__ __launch_bounds__(256) void finalize_kernel(
    const float* __restrict__ partials, int nb,
    const float* __restrict__ Wout, const float* __restrict__ bout,
    float* __restrict__ out, float invN)
{
    float s[5] = {0.f, 0.f, 0.f, 0.f, 0.f};
    for (int b = threadIdx.x; b < nb; b += 256) {
        #pragma unroll
        for (int k = 0; k < 5; ++k) s[k] += partials[b * 5 + k];
    }
    #pragma unroll
    for (int k = 0; k < 5; ++k) {
        float v = s[k];
        for (int off = 32; off > 0; off >>= 1) v += __shfl_down(v, off);
        s[k] = v;
    }
    __shared__ float lred[4][5];
    int wid = threadIdx.x >> 6, lane = threadIdx.x & 63;
    if (lane == 0) {
        #pragma unroll
        for (int k = 0; k < 5; ++k) lred[wid][k] = s[k];
    }
    __syncthreads();
    if (threadIdx.x == 0) {
        float pooled[5];
        #pragma unroll
        for (int i = 0; i < 5; ++i)
            pooled[i] = (lred[0][i] + lred[1][i] + lred[2][i] + lred[3][i]) * invN;
        float lg[10], mx = -1e30f;
        #pragma unroll
        for (int j = 0; j < 10; ++j) {
            float t = bout[j];
            #pragma unroll
            for (int i = 0; i < 5; ++i) t += Wout[j*5+i] * pooled[i];
            lg[j] = t;
            mx = fmaxf(mx, t);
        }
        float se = 0.f;
        #pragma unroll
        for (int j = 0; j < 10; ++j) { lg[j] = expf(lg[j] - mx); se += lg[j]; }
        float inv = 1.0f / se;
        #pragma unroll
        for (int j = 0; j < 10; ++j) out[j] = lg[j] * inv;
    }
}

extern "C" void kernel_launch(void* const* d_in, const int* in_sizes, int n_in,
                              void* d_out, int out_size, void* d_ws, size_t ws_size,
                              hipStream_t stream) {
    const float* pos  = (const float*)d_in[0];
    const int*   esrc = (const int*)d_in[1];
    const int*   edst = (const int*)d_in[2];
    const float* W0_1 = (const float*)d_in[3];
    const float* W1_1 = (const float*)d_in[4];
    const float* b_1  = (const float*)d_in[5];
    const float* Wg1  = (const float*)d_in[6];
    const float* bg1  = (const float*)d_in[7];
    const float* W0_2 = (const float*)d_in[8];
    const float* W1_2 = (const float*)d_in[9];
    const float* b_2  = (const float*)d_in[10];
    const float* Wg2  = (const float*)d_in[11];
    const float* bg2  = (const float*)d_in[12];
    const float* W0_3 = (const float*)d_in[13];
    const float* b_3  = (const float*)d_in[14];
    const float* Wg3  = (const float*)d_in[15];
    const float* bg3  = (const float*)d_in[16];
    const float* Wout = (const float*)d_in[17];
    const float* bout = (const float*)d_in[18];

    const int N = in_sizes[0] / 3;
    const int E = in_sizes[1];
    const int nblocks = (N + 255) / 256;
    const int P = (E + EPB - 1) / EPB;
    const int packBlocks = (N + 511) / 512;

    // ---- layout search over replica count ----
    {
        const int r2c[4] = {16, 8, 4, 2};
        for (int a = 0; a < 4; ++a) {
            int R2 = r2c[a];
            size_t off = 16384;                                      // partials
            size_t o_ctr  = off; off += 512;                         // done + rtick
            size_t o_pos4 = off; off += ((size_t)N * 16 + 255) & ~(size_t)255;
            size_t o_reps = off; off += (size_t)R2 * REP2 * 8;
            size_t o_cnts = off; off += ((size_t)P * NRG2 * 4 + 255) & ~(size_t)255;
            size_t o_gbuf = off; off += (size_t)P * EPB * 4;
            if (off > ws_size) continue;

            float*  partials = (float*)d_ws;
            u32*    done     = (u32*)((char*)d_ws + o_ctr);
            u32*    rtick    = (u32*)((char*)d_ws + o_ctr + 64);
            float4* pos4     = (float4*)((char*)d_ws + o_pos4);
            u64*    reps     = (u64*)((char*)d_ws + o_reps);
            u32*    cnts     = (u32*)((char*)d_ws + o_cnts);
            u32*    gbuf     = (u32*)((char*)d_ws + o_gbuf);

            scatter_pack_kernel<<<P + packBlocks, 512, 0, stream>>>(
                pos, pos4, esrc, edst, gbuf, cnts, done, rtick, E, N, P);
            gather_node_kernel<<<NRG2 * R2, 256, 0, stream>>>(pos4, gbuf, cnts,
                reps, rtick, done, partials, P, R2, N,
                W0_1, W1_1, b_1, Wg1, bg1,
                W0_2, W1_2, b_2, Wg2, bg2,
                W0_3, b_3, Wg3, bg3,
                Wout, bout, (float*)d_out, 1.0f / (float)N);
            return;
        }
    }

    // fallback: round-6 LDS range-bin kernel + node + finalize
    {
        float* partials = (float*)d_ws;
        u64* reps = (u64*)((char*)d_ws + 16384);
        const size_t repStride = (size_t)NRANGE * NPR;
        size_t avail = ws_size > 16384 ? ws_size - 16384 : 0;
        int C = (int)(avail / (repStride * 8));
        if (C > 48) C = 48;
        C &= ~7;
        if (C >= 8) {
            int span = (int)((((size_t)E + C - 1) / C + 3) & ~(size_t)3);
            edge_bin_kernel<<<NRANGE * C, 256, 0, stream>>>(pos, esrc, edst, reps, E, span);
            node_kernel<<<nblocks, 256, 0, stream>>>(reps, repStride, C,
                W0_1, W1_1, b_1, Wg1, bg1,
                W0_2, W1_2, b_2, Wg2, bg2,
                W0_3, b_3, Wg3, bg3,
                partials, N);
            finalize_kernel<<<1, 256, 0, stream>>>(partials, nblocks, Wout, bout,
                                                   (float*)d_out, 1.0f / (float)N);
        }
    }
}

// Round 18
// 74.167 us; speedup vs baseline: 2.6976x; 2.6976x over previous
//
#include <hip/hip_runtime.h>
#include <math.h>

#define SQRT3F 1.7320508075688772f
#define INV_SQRT3F 0.57735026918962576f
typedef unsigned long long u64;
typedef unsigned int u32;

// bin packing: [x:19][y:19][z:19][count:7], per-addend scale 1024, bias 2048
#define PK_SCALE 1024.0f
#define PK_MASK  0x7FFFFull

// main path: 2048-node ranges, 4B topology records, block counting-sort
#define NPR2   2048
#define NRG2   49                       // 49*2048 = 100352 >= N
#define REP2   ((size_t)NRG2 * NPR2)    // u64 per replica
#define EPB    4096                     // edges per scatter block

// fallback (round-6 kernel)
#define NPR    4096
#define NRANGE 25

__device__ __forceinline__ float gelu_exact(float x) {
    return 0.5f * x * (1.0f + erff(x * 0.70710678118654752f));
}

// fp32 sh components -> packed bin addend (scale 1024, bias 2048 per addend)
__device__ __forceinline__ u64 sh_to_w(float rx, float ry, float rz) {
    float rr = sqrtf(rx*rx + ry*ry + rz*rz);
    float inv = (SQRT3F * PK_SCALE) / fmaxf(rr, 1e-9f);
    u32 ax = (u32)__float2int_rn(rx * inv) + 2048u;
    u32 ay = (u32)__float2int_rn(ry * inv) + 2048u;
    u32 az = (u32)__float2int_rn(rz * inv) + 2048u;
    return (u64)ax | ((u64)ay << 19) | ((u64)az << 38) | (1ull << 57);
}

// ---- Phase 1 (fused): blocks [0,P) counting-sort records; blocks [P,..)
// pack pos->float4. The two jobs are independent; fusing removes a launch.
__global__ __launch_bounds__(1024) void scatter_pack_kernel(
    const float* __restrict__ pos, float4* __restrict__ pos4,
    const int* __restrict__ src, const int* __restrict__ dst,
    u32* __restrict__ gbuf, u32* __restrict__ cnts, u32* __restrict__ done,
    int E, int N, int P)
{
    const int p = blockIdx.x;
    if (p >= P) {                        // ---- pack duty ----
        int i = (p - P) * 1024 + (int)threadIdx.x;
        if (i < N) pos4[i] = make_float4(pos[3*i], pos[3*i+1], pos[3*i+2], 0.f);
        if (p == P && threadIdx.x == 0) *done = 0;
        return;
    }

    __shared__ u32 hist[NRG2];
    __shared__ u32 base[NRG2];
    __shared__ u32 place[NRG2];
    __shared__ u32 recbuf[EPB];
    if (threadIdx.x < NRG2) hist[threadIdx.x] = 0;
    __syncthreads();

    const int start = p * EPB;
    int end = start + EPB;
    if (end > E) end = E;

    int nk = 0;
    int d[4], s[4], r[4];
    u32 rec[4];
    int i0 = start + (int)threadIdx.x * 4;
    if (i0 + 4 <= end) {
        int4 d4 = *reinterpret_cast<const int4*>(dst + i0);
        int4 s4 = *reinterpret_cast<const int4*>(src + i0);
        d[0]=d4.x; d[1]=d4.y; d[2]=d4.z; d[3]=d4.w;
        s[0]=s4.x; s[1]=s4.y; s[2]=s4.z; s[3]=s4.w;
        nk = 4;
    } else if (i0 < end) {
        nk = end - i0;
        for (int k = 0; k < nk; ++k) { d[k] = dst[i0+k]; s[k] = src[i0+k]; }
    }
    for (int k = 0; k < nk; ++k) {
        r[k] = d[k] >> 11;
        rec[k] = ((u32)s[k] << 11) | ((u32)d[k] & 2047u);
    }
    for (int k = 0; k < nk; ++k) atomicAdd(&hist[r[k]], 1u);
    __syncthreads();

    // single-wave shfl inclusive scan over 49 entries
    if (threadIdx.x < 64) {
        int lane = threadIdx.x;
        u32 h = (lane < NRG2) ? hist[lane] : 0;
        u32 v = h;
        #pragma unroll
        for (int off = 1; off < 64; off <<= 1) {
            u32 t = __shfl_up(v, off);
            if (lane >= off) v += t;
        }
        if (lane < NRG2) { base[lane] = v - h; place[lane] = v - h; }
    }
    __syncthreads();

    for (int k = 0; k < nk; ++k) {
        u32 idx = atomicAdd(&place[r[k]], 1u);
        recbuf[idx] = rec[k];
    }
    __syncthreads();

    const int total = end - start;
    u32* out = gbuf + (size_t)p * EPB;
    for (int j = threadIdx.x; j < total; j += 1024) out[j] = recbuf[j];
    if (threadIdx.x < NRG2)
        cnts[p * NRG2 + threadIdx.x] = (base[threadIdx.x] << 16) | hist[threadIdx.x];
}

// ---- Phase 2: gather. Dense slices; pd via hot 32KB L1 window; 2 recs/lane.
__global__ __launch_bounds__(512, 8) void gather_kernel(
    const float4* __restrict__ pos4,
    const u32* __restrict__ gbuf, const u32* __restrict__ cnts,
    u64* __restrict__ reps, int P, int R2, int N)
{
    __shared__ u64 bins[NPR2];       // 16 KB
    __shared__ u32 segn[256];
    const int r  = blockIdx.x % NRG2;
    const int c2 = blockIdx.x / NRG2;
    const int base = r * NPR2;
    const float4* posd = pos4 + base;    // 32KB hot window, L1-resident

    for (int j = threadIdx.x; j < NPR2; j += 512) bins[j] = 0;
    const int nseg = (P - c2 + R2 - 1) / R2;
    for (int t = threadIdx.x; t < nseg; t += 512)
        segn[t] = cnts[(c2 + t * R2) * NRG2 + r];
    __syncthreads();

    const int wid = threadIdx.x >> 6, lane = threadIdx.x & 63;
    for (int sgi = wid; sgi < nseg; sgi += 8) {          // wave-per-segment
        const int p = c2 + sgi * R2;
        const u32 bc = segn[sgi];
        const u32 n = bc & 0xFFFFu;
        const u32* seg = gbuf + (size_t)p * EPB + (bc >> 16);
        for (u32 t = lane; t < n; t += 128) {            // 2 records in flight
            u32 rec0 = seg[t];
            bool h1 = (t + 64) < n;
            u32 rec1 = h1 ? seg[t + 64] : 0;
            u32 j0 = rec0 & 2047u, s0 = rec0 >> 11;
            float4 ps0 = pos4[s0];                       // random, L2
            float4 pd0 = posd[j0];                       // L1 window
            u32 j1 = rec1 & 2047u, s1 = rec1 >> 11;
            float4 ps1, pd1;
            if (h1) { ps1 = pos4[s1]; pd1 = posd[j1]; }
            atomicAdd(&bins[j0], sh_to_w(pd0.x-ps0.x, pd0.y-ps0.y, pd0.z-ps0.z));
            if (h1)
                atomicAdd(&bins[j1], sh_to_w(pd1.x-ps1.x, pd1.y-ps1.y, pd1.z-ps1.z));
        }
    }
    __syncthreads();

    u64* outp = reps + (size_t)c2 * REP2 + base;
    for (int j = threadIdx.x; j < NPR2; j += 512) outp[j] = bins[j];
}

// ---- Fallback (round-6): LDS range-bin with wave compaction ---------------
__global__ __launch_bounds__(256, 4) void edge_bin_kernel(
    const float* __restrict__ pos,
    const int* __restrict__ src,
    const int* __restrict__ dst,
    u64* __restrict__ reps, int E, int span)
{
    __shared__ u64 bins[NPR];
    __shared__ u32 q[4][128];
    const int g = blockIdx.x;
    const int xcd = g & 7;
    const int slot = g >> 3;
    const int c = xcd + 8 * (slot / NRANGE);
    const int r = slot % NRANGE;
    const int base = r * NPR;
    const int lane = threadIdx.x & 63;
    const int wid  = threadIdx.x >> 6;
    const u64 ltmask = (1ull << lane) - 1ull;

    for (int j = threadIdx.x; j < NPR; j += 256) bins[j] = 0;
    __syncthreads();

    const int start = c * span;
    int end = start + span;
    if (end > E) end = E;
    const int niter = (end > start) ? ((end - start + 1023) >> 10) : 0;
    int qcount = 0;

    auto process = [&](u32 i2) {
        int s2 = src[i2]; int d2 = dst[i2];
        u32 j = (u32)(d2 - base);
        atomicAdd(&bins[j], sh_to_w(pos[3*d2+0]-pos[3*s2+0],
                                    pos[3*d2+1]-pos[3*s2+1],
                                    pos[3*d2+2]-pos[3*s2+2]));
    };

    for (int t = 0; t < niter; ++t) {
        int i0 = start + ((int)threadIdx.x << 2) + (t << 10);
        int4 d4 = make_int4(-1, -1, -1, -1);
        if (i0 + 4 <= end) d4 = *reinterpret_cast<const int4*>(dst + i0);
        else if (i0 < end) for (int k = 0; i0 + k < end; ++k) (&d4.x)[k] = dst[i0 + k];
        #pragma unroll
        for (int k = 0; k < 4; ++k) {
            int i = i0 + k;
            bool in = (i < end) && ((u32)((&d4.x)[k] - base) < NPR);
            u64 mask = __ballot(in);
            if (in) q[wid][qcount + __popcll(mask & ltmask)] = (u32)i;
            qcount += (int)__popcll(mask);
            if (qcount >= 64) { qcount -= 64; process(q[wid][qcount + lane]); }
        }
    }
    if (lane < qcount) process(q[wid][lane]);
    __syncthreads();

    u64* outp = reps + (size_t)c * ((size_t)NRANGE * NPR) + base;
    for (int j = threadIdx.x; j < NPR; j += 256) outp[j] = bins[j];
}

// ---- node: sum replicas -> decode -> 3-layer net -> partials (+finalize) --
template<bool FUSE>
__global__ __launch_bounds__(256) void node_kernel(
    const u64* __restrict__ reps, size_t repStride, int R,
    const float* __restrict__ W0_1, const float* __restrict__ W1_1, const float* __restrict__ b_1,
    const float* __restrict__ Wg1,  const float* __restrict__ bg1,
    const float* __restrict__ W0_2, const float* __restrict__ W1_2, const float* __restrict__ b_2,
    const float* __restrict__ Wg2,  const float* __restrict__ bg2,
    const float* __restrict__ W0_3, const float* __restrict__ b_3,
    const float* __restrict__ Wg3,  const float* __restrict__ bg3,
    float* __restrict__ partials, int N,
    const float* __restrict__ Wout, const float* __restrict__ bout,
    float* __restrict__ out, float invN, u32* __restrict__ done)
{
    int d = blockIdx.x * blockDim.x + threadIdx.x;
    float sf[5] = {0.f, 0.f, 0.f, 0.f, 0.f};

    if (d < N) {
        u64 w = 0;
        int r = 0;
        for (; r + 4 <= R; r += 4) {
            u64 a0 = reps[(size_t)(r+0) * repStride + (u32)d];
            u64 a1 = reps[(size_t)(r+1) * repStride + (u32)d];
            u64 a2 = reps[(size_t)(r+2) * repStride + (u32)d];
            u64 a3 = reps[(size_t)(r+3) * repStride + (u32)d];
            w += a0 + a1 + a2 + a3;
        }
        for (; r < R; ++r) w += reps[(size_t)r * repStride + (u32)d];
        u32 deg = (u32)(w >> 57);
        if (deg > 0) {
            long long bias = (long long)deg << 11;
            float invdS = 1.0f / (PK_SCALE * (float)deg);
            float m[3];
            m[0] = (float)((long long)( w        & PK_MASK) - bias) * invdS;
            m[1] = (float)((long long)((w >> 19) & PK_MASK) - bias) * invdS;
            m[2] = (float)((long long)((w >> 38) & PK_MASK) - bias) * invdS;

            float s1[5], v1[5][3];
            #pragma unroll
            for (int i = 0; i < 5; ++i) {
                s1[i] = W0_1[i] + b_1[i];
                #pragma unroll
                for (int c = 0; c < 3; ++c) v1[i][c] = W1_1[i*3+c] * m[c];
            }
            float g1[10];
            #pragma unroll
            for (int j = 0; j < 10; ++j) {
                float t = bg1[j];
                #pragma unroll
                for (int i = 0; i < 5; ++i) t += Wg1[j*5+i] * s1[i];
                g1[j] = gelu_exact(t);
            }
            #pragma unroll
            for (int i = 0; i < 5; ++i) {
                s1[i] *= g1[i];
                #pragma unroll
                for (int c = 0; c < 3; ++c) v1[i][c] *= g1[5+i];
            }

            float dot1[5];
            #pragma unroll
            for (int i = 0; i < 5; ++i)
                dot1[i] = (v1[i][0]*m[0] + v1[i][1]*m[1] + v1[i][2]*m[2]) * INV_SQRT3F;
            float s2[5];
            #pragma unroll
            for (int o = 0; o < 5; ++o) {
                float t = b_2[o];
                #pragma unroll
                for (int i = 0; i < 5; ++i) t += W0_2[o*10+i] * s1[i];
                #pragma unroll
                for (int i = 0; i < 5; ++i) t += W0_2[o*10+5+i] * dot1[i];
                s2[o] = t;
            }
            float v2[5][3];
            #pragma unroll
            for (int o = 0; o < 5; ++o) {
                #pragma unroll
                for (int c = 0; c < 3; ++c) {
                    float t = 0.f;
                    #pragma unroll
                    for (int i = 0; i < 5; ++i) {
                        t += W1_2[(o*10+i)*3+c]   * (s1[i] * m[c]);
                        t += W1_2[(o*10+5+i)*3+c] * v1[i][c];
                    }
                    v2[o][c] = t;
                }
            }
            float g2[10];
            #pragma unroll
            for (int j = 0; j < 10; ++j) {
                float t = bg2[j];
                #pragma unroll
                for (int i = 0; i < 5; ++i) t += Wg2[j*5+i] * s2[i];
                g2[j] = gelu_exact(t);
            }
            #pragma unroll
            for (int i = 0; i < 5; ++i) {
                s2[i] *= g2[i];
                #pragma unroll
                for (int c = 0; c < 3; ++c) v2[i][c] *= g2[5+i];
            }

            float dot2[5];
            #pragma unroll
            for (int i = 0; i < 5; ++i)
                dot2[i] = (v2[i][0]*m[0] + v2[i][1]*m[1] + v2[i][2]*m[2]) * INV_SQRT3F;
            float s3[5];
            #pragma unroll
            for (int o = 0; o < 5; ++o) {
                float t = b_3[o];
                #pragma unroll
                for (int i = 0; i < 5; ++i) t += W0_3[o*10+i] * s2[i];
                #pragma unroll
                for (int i = 0; i < 5; ++i) t += W0_3[o*10+5+i] * dot2[i];
                s3[o] = t;
            }
            #pragma unroll
            for (int i = 0; i < 5; ++i) {
                float t = bg3[i];
                #pragma unroll
                for (int j = 0; j < 5; ++j) t += Wg3[i*5+j] * s3[j];
                sf[i] = gelu_exact(t) * s3[i];
            }
        }
    }

    #pragma unroll
    for (int k = 0; k < 5; ++k) {
        float v = sf[k];
        for (int off = 32; off > 0; off >>= 1) v += __shfl_down(v, off);
        sf[k] = v;
    }
    __shared__ float lred[4][5];
    __shared__ int islast;
    int wid = threadIdx.x >> 6, lane = threadIdx.x & 63;
    if (lane == 0) {
        #pragma unroll
        for (int k = 0; k < 5; ++k) lred[wid][k] = sf[k];
    }
    __syncthreads();
    if (threadIdx.x == 0) {
        #pragma unroll
        for (int k = 0; k < 5; ++k)
            partials[blockIdx.x * 5 + k] = lred[0][k] + lred[1][k] + lred[2][k] + lred[3][k];
    }

    if (FUSE) {
        if (threadIdx.x == 0) {
            __threadfence();
            u32 old = atomicAdd(done, 1u);
            islast = (old == gridDim.x - 1);
        }
        __syncthreads();
        if (!islast) return;
        __threadfence();
        float s[5] = {0.f, 0.f, 0.f, 0.f, 0.f};
        for (int b = threadIdx.x; b < (int)gridDim.x; b += 256) {
            #pragma unroll
            for (int k = 0; k < 5; ++k) s[k] += partials[b * 5 + k];
        }
        #pragma unroll
        for (int k = 0; k < 5; ++k) {
            float v = s[k];
            for (int off = 32; off > 0; off >>= 1) v += __shfl_down(v, off);
            s[k] = v;
        }
        __syncthreads();
        if (lane == 0) {
            #pragma unroll
            for (int k = 0; k < 5; ++k) lred[wid][k] = s[k];
        }
        __syncthreads();
        if (threadIdx.x == 0) {
            float pooled[5];
            #pragma unroll
            for (int i = 0; i < 5; ++i)
                pooled[i] = (lred[0][i] + lred[1][i] + lred[2][i] + lred[3][i]) * invN;
            float lg[10], mx = -1e30f;
            #pragma unroll
            for (int j = 0; j < 10; ++j) {
                float t = bout[j];
                #pragma unroll
                for (int i = 0; i < 5; ++i) t += Wout[j*5+i] * pooled[i];
                lg[j] = t;
                mx = fmaxf(mx, t);
            }
            float se = 0.f;
            #pragma unroll
            for (int j = 0; j < 10; ++j) { lg[j] = expf(lg[j] - mx); se += lg[j]; }
            float inv = 1.0f / se;
            #pragma unroll
            for (int j = 0; j < 10; ++j) out[j] = lg[j] * inv;
        }
    }
}

// standalone finalize (fallback path only)
__global__ __launch_bounds__(256) void finalize_kernel(
    const float* __restrict__ partials, int nb,
    const float* __restrict__ Wout, const float* __restrict__ bout,
    float* __restrict__ out, float invN)
{
    float s[5] = {0.f, 0.f, 0.f, 0.f, 0.f};
    for (int b = threadIdx.x; b < nb; b += 256) {
        #pragma unroll
        for (int k = 0; k < 5; ++k) s[k] += partials[b * 5 + k];
    }
    #pragma unroll
    for (int k = 0; k < 5; ++k) {
        float v = s[k];
        for (int off = 32; off > 0; off >>= 1) v += __shfl_down(v, off);
        s[k] = v;
    }
    __shared__ float lred[4][5];
    int wid = threadIdx.x >> 6, lane = threadIdx.x & 63;
    if (lane == 0) {
        #pragma unroll
        for (int k = 0; k < 5; ++k) lred[wid][k] = s[k];
    }
    __syncthreads();
    if (threadIdx.x == 0) {
        float pooled[5];
        #pragma unroll
        for (int i = 0; i < 5; ++i)
            pooled[i] = (lred[0][i] + lred[1][i] + lred[2][i] + lred[3][i]) * invN;
        float lg[10], mx = -1e30f;
        #pragma unroll
        for (int j = 0; j < 10; ++j) {
            float t = bout[j];
            #pragma unroll
            for (int i = 0; i < 5; ++i) t += Wout[j*5+i] * pooled[i];
            lg[j] = t;
            mx = fmaxf(mx, t);
        }
        float se = 0.f;
        #pragma unroll
        for (int j = 0; j < 10; ++j) { lg[j] = expf(lg[j] - mx); se += lg[j]; }
        float inv = 1.0f / se;
        #pragma unroll
        for (int j = 0; j < 10; ++j) out[j] = lg[j] * inv;
    }
}

extern "C" void kernel_launch(void* const* d_in, const int* in_sizes, int n_in,
                              void* d_out, int out_size, void* d_ws, size_t ws_size,
                              hipStream_t stream) {
    const float* pos  = (const float*)d_in[0];
    const int*   esrc = (const int*)d_in[1];
    const int*   edst = (const int*)d_in[2];
    const float* W0_1 = (const float*)d_in[3];
    const float* W1_1 = (const float*)d_in[4];
    const float* b_1  = (const float*)d_in[5];
    const float* Wg1  = (const float*)d_in[6];
    const float* bg1  = (const float*)d_in[7];
    const float* W0_2 = (const float*)d_in[8];
    const float* W1_2 = (const float*)d_in[9];
    const float* b_2  = (const float*)d_in[10];
    const float* Wg2  = (const float*)d_in[11];
    const float* bg2  = (const float*)d_in[12];
    const float* W0_3 = (const float*)d_in[13];
    const float* b_3  = (const float*)d_in[14];
    const float* Wg3  = (const float*)d_in[15];
    const float* bg3  = (const float*)d_in[16];
    const float* Wout = (const float*)d_in[17];
    const float* bout = (const float*)d_in[18];

    const int N = in_sizes[0] / 3;
    const int E = in_sizes[1];
    const int nblocks = (N + 255) / 256;
    const int P = (E + EPB - 1) / EPB;
    const int packBlocks = (N + 1023) / 1024;

    // ---- layout search over replica count ----
    {
        const int r2c[3] = {16, 8, 4};
        for (int a = 0; a < 3; ++a) {
            int R2 = r2c[a];
            size_t off = 16384;                                      // partials
            size_t o_ctr  = off; off += 256;                         // done
            size_t o_pos4 = off; off += ((size_t)N * 16 + 255) & ~(size_t)255;
            size_t o_reps = off; off += (size_t)R2 * REP2 * 8;
            size_t o_cnts = off; off += ((size_t)P * NRG2 * 4 + 255) & ~(size_t)255;
            size_t o_gbuf = off; off += (size_t)P * EPB * 4;
            if (off > ws_size) continue;

            float*  partials = (float*)d_ws;
            u32*    done     = (u32*)((char*)d_ws + o_ctr);
            float4* pos4     = (float4*)((char*)d_ws + o_pos4);
            u64*    reps     = (u64*)((char*)d_ws + o_reps);
            u32*    cnts     = (u32*)((char*)d_ws + o_cnts);
            u32*    gbuf     = (u32*)((char*)d_ws + o_gbuf);

            scatter_pack_kernel<<<P + packBlocks, 1024, 0, stream>>>(
                pos, pos4, esrc, edst, gbuf, cnts, done, E, N, P);
            gather_kernel<<<NRG2 * R2, 512, 0, stream>>>(pos4, gbuf, cnts,
                reps, P, R2, N);
            node_kernel<true><<<nblocks, 256, 0, stream>>>(reps, REP2, R2,
                W0_1, W1_1, b_1, Wg1, bg1,
                W0_2, W1_2, b_2, Wg2, bg2,
                W0_3, b_3, Wg3, bg3,
                partials, N, Wout, bout, (float*)d_out, 1.0f / (float)N, done);
            return;
        }
    }

    // fallback: round-6 LDS range-bin kernel + node + finalize
    {
        float* partials = (float*)d_ws;
        u64* reps = (u64*)((char*)d_ws + 16384);
        const size_t repStride = (size_t)NRANGE * NPR;
        size_t avail = ws_size > 16384 ? ws_size - 16384 : 0;
        int C = (int)(avail / (repStride * 8));
        if (C > 48) C = 48;
        C &= ~7;
        if (C >= 8) {
            int span = (int)((((size_t)E + C - 1) / C + 3) & ~(size_t)3);
            edge_bin_kernel<<<NRANGE * C, 256, 0, stream>>>(pos, esrc, edst, reps, E, span);
            node_kernel<false><<<nblocks, 256, 0, stream>>>(reps, repStride, C,
                W0_1, W1_1, b_1, Wg1, bg1,
                W0_2, W1_2, b_2, Wg2, bg2,
                W0_3, b_3, Wg3, bg3,
                partials, N, nullptr, nullptr, nullptr, 0.f, nullptr);
            finalize_kernel<<<1, 256, 0, stream>>>(partials, nblocks, Wout, bout,
                                                   (float*)d_out, 1.0f / (float)N);
        }
    }
}